// Round 7
// baseline (2377.506 us; speedup 1.0000x reference)
//
#include <hip/hip_runtime.h>
#include <hip/hip_fp16.h>
#include <math.h>

#ifndef M_PI
#define M_PI 3.14159265358979323846
#endif

// Problem constants
#define BB 2
#define VV 180
#define RR 32
#define CC 512
#define NPIX 512

#define PADL 106     // left padding of t-range
#define PW 724       // padded width: t_real in [-106, 617]
#define TCEN 362     // index recentering offset

// pair-orbit backprojection tiling
#define SH3 8        // rep-rows per block
#define CHP 2        // angle-PAIRS per LDS chunk
#define NCHP 45      // 45 * 2 = 90 pairs = 180 angles

// fallback tiling (round-3 kernels)
#define SH 16
#define CH2 6
#define NCHUNK2 30

// ws layout (floats):
//   [0,1024)      h_ext (impulse response, duplicated, scaled by pi/V)
//   [1024,1384)   legacy trig: cos[180] | sin[180]          (fallback path)
//   [1408,1768)   trig2: interleaved (cos,sin) float2[180]  (pair path uses first 90)
//   [2048,...)    pair path: fp16 table [64 slices][90 pairs][724] uint2 cells = 33.4 MB
//                 fallback:  filt [b][r][v][c] = 23.6 MB
#define TAB_OFF 2048
#define FILT_OFF 2048

// ---------------------------------------------------------------------------
// Kernel A: ramp-filter impulse response h[k] (scaled by pi/V) + angle tables.
// ---------------------------------------------------------------------------
__global__ void precompute_kernel(float* __restrict__ ws) {
    int j = blockIdx.x * blockDim.x + threadIdx.x;  // 0..511
    if (j < 512) {
        float s = 0.f;
        for (int m = 1; m < 512; ++m) {             // m=0 term has ramp=0
            int p = (m * j) & 511;                  // exact (m*j) mod 512
            float ang = (float)(2.0 * M_PI / 512.0) * (float)p;
            int mm = m < 512 - m ? m : 512 - m;
            float ramp = 2.0f * (float)mm * (1.0f / 512.0f);
            s += ramp * cosf(ang);
        }
        s *= (1.0f / 512.0f);
        s *= (float)(M_PI / (double)VV);            // fold backprojection scale
        ws[j] = s;
        ws[j + 512] = s;                            // h_ext[j+512] == h[j]
    }
    if (j < VV) {
        float th = (float)((double)j * M_PI / 180.0);
        float c = cosf(th), sn = sinf(th);
        ws[1024 + j] = c;
        ws[1024 + 180 + j] = sn;
        ws[1408 + 2 * j] = c;
        ws[1408 + 2 * j + 1] = sn;
    }
}

// ---------------------------------------------------------------------------
// Kernel B (pair path): PAIR convolution. One block = 8 detector rows of the
// angle pair (p, p+90). Epilogue writes FULL 8-byte table cells coalesced:
//   cell[cx] = (half2(f0_p, d_p), half2(f0_{p+90}, d_{p+90}))
// value(u) = f0 + w*d, pads have d=0 (edge clamp).
// ---------------------------------------------------------------------------
__global__ __launch_bounds__(128) void conv_pair_kernel(const float* __restrict__ sino,
                                                        const float* __restrict__ ws,
                                                        uint2* __restrict__ table) {
    __shared__ float rows_s[16 * 512];  // 32 KiB: rows 0-7 = angle p, 8-15 = p+90
    __shared__ float h_s[1024];         // 4 KiB
    int t = threadIdx.x;
    int blk = blockIdx.x;               // 0..719
    int tq = blk / 90;                  // 0..7
    int p = blk - tq * 90;              // pair index 0..89
    int q = tq & 3;                     // row-quarter (8 rows each)
    int b = tq >> 2;                    // batch

    const float4* srcA = (const float4*)(sino + (((size_t)(b * 180 + p)) * 32 + q * 8) * 512);
    const float4* srcB = (const float4*)(sino + (((size_t)(b * 180 + p + 90)) * 32 + q * 8) * 512);
    float4* rows4 = (float4*)rows_s;
    for (int i = t; i < 1024; i += 128) rows4[i] = srcA[i];
    for (int i = t; i < 1024; i += 128) rows4[1024 + i] = srcB[i];
    for (int i = t; i < 1024; i += 128) h_s[i] = ws[i];
    __syncthreads();

    int wave = t >> 6;
    int lane = t & 63;
    int row0 = wave * 8;

    float acc[8][8];
#pragma unroll
    for (int j = 0; j < 8; ++j)
#pragma unroll
        for (int i = 0; i < 8; ++i) acc[j][i] = 0.f;

    for (int k = 0; k < 512; k += 4) {
        float4 rv[8];
#pragma unroll
        for (int j = 0; j < 8; ++j)
            rv[j] = *(const float4*)&rows_s[(row0 + j) * 512 + k];
#pragma unroll
        for (int u = 0; u < 4; ++u) {
            float hv[8];
            int base = lane - (k + u) + 512;   // in [1, 1023]
#pragma unroll
            for (int i = 0; i < 8; ++i) hv[i] = h_s[base + 64 * i];
#pragma unroll
            for (int j = 0; j < 8; ++j) {
                float rj = (u == 0) ? rv[j].x : (u == 1) ? rv[j].y : (u == 2) ? rv[j].z : rv[j].w;
#pragma unroll
                for (int i = 0; i < 8; ++i) acc[j][i] = fmaf(rj, hv[i], acc[j][i]);
            }
        }
    }

    // Round-trip filtered rows through LDS, emit full fp16 cells coalesced.
    __syncthreads();
#pragma unroll
    for (int j = 0; j < 8; ++j)
#pragma unroll
        for (int i = 0; i < 8; ++i)
            rows_s[(row0 + j) * 512 + lane + 64 * i] = acc[j][i];
    __syncthreads();

    for (int jj = 0; jj < 8; ++jj) {
        const float* frv = rows_s + jj * 512;          // angle p
        const float* frw = rows_s + (8 + jj) * 512;    // angle p+90
        int slice = b * 32 + q * 8 + jj;
        uint2* trow = table + ((size_t)slice * 90 + p) * PW;
        for (int cx = t; cx < PW; cx += 128) {
            int s0 = cx - PADL;
            int i0 = min(max(s0, 0), 511);
            int i1 = min(max(s0 + 1, 0), 511);
            float f0v = frv[i0];
            float dv = frv[i1] - f0v;
            float f0w = frw[i0];
            float dw = frw[i1] - f0w;
            __half2 hv = __floats2half2_rn(f0v, dv);   // lo=f0, hi=d
            __half2 hw = __floats2half2_rn(f0w, dw);
            uint2 cell;
            cell.x = *(unsigned int*)&hv;
            cell.y = *(unsigned int*)&hw;
            trow[cx] = cell;                           // full 8B, coalesced
        }
    }
}

// ---------------------------------------------------------------------------
// Kernel C (pair path): orbit backprojection with fp16 table. One lane = one
// 4-pixel rotation orbit. Each ds_read_b64 of (f0_v,d_v,f0_w,d_w) serves TWO
// samples. P1/P3 epilogue uses per-lane float4 stores (each output line
// written once, in one instruction) to avoid partial-line eviction churn.
// ---------------------------------------------------------------------------
__global__ __launch_bounds__(256, 8) void backproj_pairh_kernel(const uint2* __restrict__ tab,
                                                                const float2* __restrict__ trigp,
                                                                float* __restrict__ out) {
    __shared__ __align__(16) uint2 pbuf[CHP * PW];   // 11584 B
    __shared__ float2 trig_s[90];
    int t = threadIdx.x;
    int slice = blockIdx.y;             // b*32 + r
    int strip = blockIdx.x;             // 0..31
    int y0 = strip * SH3;               // rep-row offset in [0,256)
    const uint2* tslice = tab + (size_t)slice * (90 * PW);

    for (int i = t; i < 90; i += 256) trig_s[i] = trigp[i];

    float xc = (float)t + 0.5f;         // rep px = 256+t  ->  xc = px-255.5

    float acc0[SH3], acc1[SH3], acc2[SH3], acc3[SH3];
#pragma unroll
    for (int j = 0; j < SH3; ++j) { acc0[j] = 0.f; acc1[j] = 0.f; acc2[j] = 0.f; acc3[j] = 0.f; }

    for (int chunk = 0; chunk < NCHP; ++chunk) {
        __syncthreads();                // previous chunk consumed (covers trig_s on chunk 0)
        const float4* src = (const float4*)(tslice + chunk * (CHP * PW));
        float4* dst = (float4*)pbuf;
        for (int i = t; i < (CHP * PW) / 2; i += 256) dst[i] = src[i];
        __syncthreads();
#pragma unroll
        for (int pa = 0; pa < CHP; ++pa) {
            float2 cs = trig_s[chunk * CHP + pa];
            const uint2* pb = pbuf + pa * PW + TCEN;
#pragma unroll
            for (int j = 0; j < SH3; ++j) {
                float ycj = (float)(y0 + j) + 0.5f;
                float ua = fmaf(xc, cs.x, fmaf(ycj, cs.y, -0.5f));   // x c + y s - .5
                float ub = fmaf(xc, cs.y, fmaf(-ycj, cs.x, -0.5f));  // x s - y c - .5
                float uma = -1.0f - ua;
                float umb = -1.0f - ub;

                float fa = floorf(ua);  int ma  = (int)fa;  float wa  = ua  - fa;
                float fm = floorf(uma); int mma = (int)fm;  float wma = uma - fm;
                float fb = floorf(ub);  int mb  = (int)fb;  float wb  = ub  - fb;
                float fn = floorf(umb); int mmb = (int)fn;  float wmb = umb - fn;

                uint2 qa  = pb[ma];
                uint2 qma = pb[mma];
                uint2 qb  = pb[mb];
                uint2 qmb = pb[mmb];
                __half2 qa0  = *(const __half2*)&qa.x,  qa1  = *(const __half2*)&qa.y;
                __half2 qma0 = *(const __half2*)&qma.x, qma1 = *(const __half2*)&qma.y;
                __half2 qb0  = *(const __half2*)&qb.x,  qb1  = *(const __half2*)&qb.y;
                __half2 qmb0 = *(const __half2*)&qmb.x, qmb1 = *(const __half2*)&qmb.y;

                acc0[j] = fmaf(wa,  __high2float(qa0),  acc0[j]) + __low2float(qa0);   // P0 @ v
                acc1[j] = fmaf(wa,  __high2float(qa1),  acc1[j]) + __low2float(qa1);   // P1 @ v+90
                acc2[j] = fmaf(wma, __high2float(qma0), acc2[j]) + __low2float(qma0);  // P2 @ v
                acc3[j] = fmaf(wma, __high2float(qma1), acc3[j]) + __low2float(qma1);  // P3 @ v+90
                acc1[j] = fmaf(wb,  __high2float(qb0),  acc1[j]) + __low2float(qb0);   // P1 @ v
                acc2[j] = fmaf(wb,  __high2float(qb1),  acc2[j]) + __low2float(qb1);   // P2 @ v+90
                acc3[j] = fmaf(wmb, __high2float(qmb0), acc3[j]) + __low2float(qmb0);  // P3 @ v
                acc0[j] = fmaf(wmb, __high2float(qmb1), acc0[j]) + __low2float(qmb1);  // P0 @ v+90
            }
        }
    }

    int px = 256 + t;
    size_t sbase = (size_t)slice * (512 * 512);
    // P0 (rows py, lanes consecutive in x) and P2 (mirrored) - coalesced dwords.
#pragma unroll
    for (int j = 0; j < SH3; ++j) {
        int py = 256 + y0 + j;
        float v0 = acc0[j], v2 = acc2[j];
        out[sbase + (size_t)py * 512 + px]                 = v0 > 0.f ? v0 : 0.f;
        out[sbase + (size_t)(511 - py) * 512 + (511 - px)] = v2 > 0.f ? v2 : 0.f;
    }
    // P1: lane t owns row px, columns 255-y0-j (j=0..7) -> two float4 stores.
    {
        float r7 = acc1[7] > 0.f ? acc1[7] : 0.f;
        float r6 = acc1[6] > 0.f ? acc1[6] : 0.f;
        float r5 = acc1[5] > 0.f ? acc1[5] : 0.f;
        float r4 = acc1[4] > 0.f ? acc1[4] : 0.f;
        float r3 = acc1[3] > 0.f ? acc1[3] : 0.f;
        float r2 = acc1[2] > 0.f ? acc1[2] : 0.f;
        float r1 = acc1[1] > 0.f ? acc1[1] : 0.f;
        float r0 = acc1[0] > 0.f ? acc1[0] : 0.f;
        float* base = out + sbase + (size_t)px * 512 + (248 - y0);
        *(float4*)base       = make_float4(r7, r6, r5, r4);   // cols 248-y0..251-y0
        *(float4*)(base + 4) = make_float4(r3, r2, r1, r0);   // cols 252-y0..255-y0
    }
    // P3: lane t owns row 255-t, columns 256+y0+j (j=0..7) -> two float4 stores.
    {
        float r0 = acc3[0] > 0.f ? acc3[0] : 0.f;
        float r1 = acc3[1] > 0.f ? acc3[1] : 0.f;
        float r2 = acc3[2] > 0.f ? acc3[2] : 0.f;
        float r3 = acc3[3] > 0.f ? acc3[3] : 0.f;
        float r4 = acc3[4] > 0.f ? acc3[4] : 0.f;
        float r5 = acc3[5] > 0.f ? acc3[5] : 0.f;
        float r6 = acc3[6] > 0.f ? acc3[6] : 0.f;
        float r7 = acc3[7] > 0.f ? acc3[7] : 0.f;
        float* base = out + sbase + (size_t)(255 - t) * 512 + (256 + y0);
        *(float4*)base       = make_float4(r0, r1, r2, r3);   // cols 256+y0..259+y0
        *(float4*)(base + 4) = make_float4(r4, r5, r6, r7);   // cols 260+y0..263+y0
    }
}

// ===========================================================================
// Fallback path (round-3 kernels) - used only if ws_size can't hold the table.
// ===========================================================================
__global__ __launch_bounds__(128) void conv_kernel(const float* __restrict__ sino,
                                                   const float* __restrict__ ws,
                                                   float* __restrict__ filt) {
    __shared__ float rows_s[16 * 512];
    __shared__ float h_s[1024];
    int t = threadIdx.x;
    int blk = blockIdx.x;
    int bv = blk >> 1;
    int half = blk & 1;
    int b = bv / 180;
    int v = bv - b * 180;

    const float4* src4 = (const float4*)(sino + (((size_t)bv * 32) + (size_t)half * 16) * 512);
    float4* rows4 = (float4*)rows_s;
    for (int i = t; i < 2048; i += 128) rows4[i] = src4[i];
    for (int i = t; i < 1024; i += 128) h_s[i] = ws[i];
    __syncthreads();

    int wave = t >> 6;
    int lane = t & 63;
    int row0 = wave * 8;

    float acc[8][8];
#pragma unroll
    for (int j = 0; j < 8; ++j)
#pragma unroll
        for (int i = 0; i < 8; ++i) acc[j][i] = 0.f;

    for (int k = 0; k < 512; k += 4) {
        float4 rv[8];
#pragma unroll
        for (int j = 0; j < 8; ++j)
            rv[j] = *(const float4*)&rows_s[(row0 + j) * 512 + k];
#pragma unroll
        for (int u = 0; u < 4; ++u) {
            float hv[8];
            int base = lane - (k + u) + 512;
#pragma unroll
            for (int i = 0; i < 8; ++i) hv[i] = h_s[base + 64 * i];
#pragma unroll
            for (int j = 0; j < 8; ++j) {
                float rj = (u == 0) ? rv[j].x : (u == 1) ? rv[j].y : (u == 2) ? rv[j].z : rv[j].w;
#pragma unroll
                for (int i = 0; i < 8; ++i) acc[j][i] = fmaf(rj, hv[i], acc[j][i]);
            }
        }
    }

#pragma unroll
    for (int j = 0; j < 8; ++j) {
        int r = half * 16 + row0 + j;
        float* dst = filt + (((size_t)b * 32 + r) * 180 + v) * 512;
#pragma unroll
        for (int i = 0; i < 8; ++i) dst[lane + 64 * i] = acc[j][i];
    }
}

__global__ __launch_bounds__(256) void backproj_kernel(const float* __restrict__ filt,
                                                       const float* __restrict__ trig,
                                                       float* __restrict__ out) {
    __shared__ float2 pbuf[CH2][PW];
    __shared__ float trig_s[360];
    int t = threadIdx.x;
    int slice = blockIdx.y;
    int strip = blockIdx.x;
    int y0 = strip * SH;
    int lane = t & 63;
    int wave = t >> 6;
    int x0 = wave * 128;
    const float* slice_p = filt + (size_t)slice * (180 * 512);

    for (int i = t; i < 360; i += 256) trig_s[i] = trig[i];

    float xc0 = (float)(x0 + lane) - 255.5f;
    float xc1 = xc0 + 64.0f;
    float yb0 = (float)y0 - 255.5f;

    float acc[2][SH];
#pragma unroll
    for (int g = 0; g < 2; ++g)
#pragma unroll
        for (int j = 0; j < SH; ++j) acc[g][j] = 0.f;

    for (int chunk = 0; chunk < NCHUNK2; ++chunk) {
        int v0 = chunk * CH2;
        __syncthreads();
#pragma unroll 1
        for (int a = 0; a < CH2; ++a) {
            const float* prow = slice_p + (v0 + a) * 512;
            for (int cx = t; cx < PW; cx += 256) {
                int s0 = cx - PADL;
                int i0 = min(max(s0, 0), 511);
                int i1 = min(max(s0 + 1, 0), 511);
                float f0 = prow[i0];
                float d = prow[i1] - f0;
                float m = (float)(cx - TCEN);
                pbuf[a][cx] = make_float2(fmaf(-m, d, f0), d);
            }
        }
        __syncthreads();
#pragma unroll 1
        for (int a = 0; a < CH2; ++a) {
            float cth = trig_s[v0 + a];
            float sth = trig_s[180 + v0 + a];
            float ybase = fmaf(yb0, sth, 255.5f + (float)PADL - (float)TCEN);
            float t0 = fmaf(xc0, cth, ybase);
            float t1 = fmaf(xc1, cth, ybase);
            const char* pb = (const char*)pbuf;
            int aoff = a * (PW * 8) + TCEN * 8;
#pragma unroll
            for (int j = 0; j < SH; ++j) {
                int m0 = (int)floorf(t0);
                float2 g0 = *(const float2*)(pb + (m0 * 8 + aoff));
                acc[0][j] = fmaf(t0, g0.y, acc[0][j]) + g0.x;
                t0 += sth;

                int m1 = (int)floorf(t1);
                float2 g1 = *(const float2*)(pb + (m1 * 8 + aoff));
                acc[1][j] = fmaf(t1, g1.y, acc[1][j]) + g1.x;
                t1 += sth;
            }
        }
    }

    size_t obase = ((size_t)slice * 512 + (size_t)y0) * 512;
#pragma unroll
    for (int j = 0; j < SH; ++j) {
        float v0o = acc[0][j];
        float v1o = acc[1][j];
        out[obase + (size_t)j * 512 + x0 + lane] = v0o > 0.f ? v0o : 0.f;
        out[obase + (size_t)j * 512 + x0 + 64 + lane] = v1o > 0.f ? v1o : 0.f;
    }
}

extern "C" void kernel_launch(void* const* d_in, const int* in_sizes, int n_in,
                              void* d_out, int out_size, void* d_ws, size_t ws_size,
                              hipStream_t stream) {
    const float* sino = (const float*)d_in[0];
    float* out = (float*)d_out;
    float* ws = (float*)d_ws;

    size_t tableBytes = (size_t)64 * 90 * PW * 8;              // uint2 cells
    size_t needed = TAB_OFF * sizeof(float) + tableBytes;      // ~33.4 MB

    precompute_kernel<<<2, 256, 0, stream>>>(ws);
    if (ws_size >= needed) {
        uint2* table = (uint2*)(ws + TAB_OFF);
        conv_pair_kernel<<<720, 128, 0, stream>>>(sino, ws, table);
        backproj_pairh_kernel<<<dim3(32, 64), 256, 0, stream>>>(table,
                                                                (const float2*)(ws + 1408), out);
    } else {
        float* filt = ws + FILT_OFF;
        conv_kernel<<<720, 128, 0, stream>>>(sino, ws, filt);
        backproj_kernel<<<dim3(32, 64), 256, 0, stream>>>(filt, ws + 1024, out);
    }
}

// Round 8
// 1096.451 us; speedup vs baseline: 2.1684x; 2.1684x over previous
//
#include <hip/hip_runtime.h>
#include <hip/hip_fp16.h>
#include <math.h>

#ifndef M_PI
#define M_PI 3.14159265358979323846
#endif

// Problem constants
#define BB 2
#define VV 180
#define RR 32
#define CC 512
#define NPIX 512

#define PADL 106     // left padding of t-range
#define PW 724       // padded width: t_real in [-106, 617]
#define TCEN 362     // index recentering offset

// pair-orbit backprojection tiling
#define SH3 16       // rep-rows per block (16 => all output lines block-private)
#define CHP 2        // angle-PAIRS per LDS chunk
#define NCHP 45      // 45 * 2 = 90 pairs = 180 angles
#define TSTRIDE 20   // padded LDS transpose stride (dwords)

// fallback tiling (round-3 kernels)
#define SH 16
#define CH2 6
#define NCHUNK2 30

// ws layout (floats):
//   [0,1024)      h_ext (impulse response, duplicated, scaled by pi/V)
//   [1024,1384)   legacy trig: cos[180] | sin[180]          (fallback path)
//   [1408,1768)   trig2: interleaved (cos,sin) float2[180]  (pair path uses first 90)
//   [2048,...)    pair path: fp16 table [64 slices][90 pairs][724] uint2 cells = 33.4 MB
//                 fallback:  filt [b][r][v][c] = 23.6 MB
#define TAB_OFF 2048
#define FILT_OFF 2048

// ---------------------------------------------------------------------------
// Kernel A: ramp-filter impulse response h[k] (scaled by pi/V) + angle tables.
// ---------------------------------------------------------------------------
__global__ void precompute_kernel(float* __restrict__ ws) {
    int j = blockIdx.x * blockDim.x + threadIdx.x;  // 0..511
    if (j < 512) {
        float s = 0.f;
        for (int m = 1; m < 512; ++m) {             // m=0 term has ramp=0
            int p = (m * j) & 511;                  // exact (m*j) mod 512
            float ang = (float)(2.0 * M_PI / 512.0) * (float)p;
            int mm = m < 512 - m ? m : 512 - m;
            float ramp = 2.0f * (float)mm * (1.0f / 512.0f);
            s += ramp * cosf(ang);
        }
        s *= (1.0f / 512.0f);
        s *= (float)(M_PI / (double)VV);            // fold backprojection scale
        ws[j] = s;
        ws[j + 512] = s;                            // h_ext[j+512] == h[j]
    }
    if (j < VV) {
        float th = (float)((double)j * M_PI / 180.0);
        float c = cosf(th), sn = sinf(th);
        ws[1024 + j] = c;
        ws[1024 + 180 + j] = sn;
        ws[1408 + 2 * j] = c;
        ws[1408 + 2 * j + 1] = sn;
    }
}

// ---------------------------------------------------------------------------
// Kernel B (pair path): PAIR convolution. One block = 8 detector rows of the
// angle pair (p, p+90). Epilogue writes FULL 8-byte table cells coalesced:
//   cell[cx] = (half2(f0_p, d_p), half2(f0_{p+90}, d_{p+90}))
// value(u) = f0 + w*d, pads have d=0 (edge clamp).
// ---------------------------------------------------------------------------
__global__ __launch_bounds__(128) void conv_pair_kernel(const float* __restrict__ sino,
                                                        const float* __restrict__ ws,
                                                        uint2* __restrict__ table) {
    __shared__ float rows_s[16 * 512];  // 32 KiB: rows 0-7 = angle p, 8-15 = p+90
    __shared__ float h_s[1024];         // 4 KiB
    int t = threadIdx.x;
    int blk = blockIdx.x;               // 0..719
    int tq = blk / 90;                  // 0..7
    int p = blk - tq * 90;              // pair index 0..89
    int q = tq & 3;                     // row-quarter (8 rows each)
    int b = tq >> 2;                    // batch

    const float4* srcA = (const float4*)(sino + (((size_t)(b * 180 + p)) * 32 + q * 8) * 512);
    const float4* srcB = (const float4*)(sino + (((size_t)(b * 180 + p + 90)) * 32 + q * 8) * 512);
    float4* rows4 = (float4*)rows_s;
    for (int i = t; i < 1024; i += 128) rows4[i] = srcA[i];
    for (int i = t; i < 1024; i += 128) rows4[1024 + i] = srcB[i];
    for (int i = t; i < 1024; i += 128) h_s[i] = ws[i];
    __syncthreads();

    int wave = t >> 6;
    int lane = t & 63;
    int row0 = wave * 8;

    float acc[8][8];
#pragma unroll
    for (int j = 0; j < 8; ++j)
#pragma unroll
        for (int i = 0; i < 8; ++i) acc[j][i] = 0.f;

    for (int k = 0; k < 512; k += 4) {
        float4 rv[8];
#pragma unroll
        for (int j = 0; j < 8; ++j)
            rv[j] = *(const float4*)&rows_s[(row0 + j) * 512 + k];
#pragma unroll
        for (int u = 0; u < 4; ++u) {
            float hv[8];
            int base = lane - (k + u) + 512;   // in [1, 1023]
#pragma unroll
            for (int i = 0; i < 8; ++i) hv[i] = h_s[base + 64 * i];
#pragma unroll
            for (int j = 0; j < 8; ++j) {
                float rj = (u == 0) ? rv[j].x : (u == 1) ? rv[j].y : (u == 2) ? rv[j].z : rv[j].w;
#pragma unroll
                for (int i = 0; i < 8; ++i) acc[j][i] = fmaf(rj, hv[i], acc[j][i]);
            }
        }
    }

    // Round-trip filtered rows through LDS, emit full fp16 cells coalesced.
    __syncthreads();
#pragma unroll
    for (int j = 0; j < 8; ++j)
#pragma unroll
        for (int i = 0; i < 8; ++i)
            rows_s[(row0 + j) * 512 + lane + 64 * i] = acc[j][i];
    __syncthreads();

    for (int jj = 0; jj < 8; ++jj) {
        const float* frv = rows_s + jj * 512;          // angle p
        const float* frw = rows_s + (8 + jj) * 512;    // angle p+90
        int slice = b * 32 + q * 8 + jj;
        uint2* trow = table + ((size_t)slice * 90 + p) * PW;
        for (int cx = t; cx < PW; cx += 128) {
            int s0 = cx - PADL;
            int i0 = min(max(s0, 0), 511);
            int i1 = min(max(s0 + 1, 0), 511);
            float f0v = frv[i0];
            float dv = frv[i1] - f0v;
            float f0w = frw[i0];
            float dw = frw[i1] - f0w;
            __half2 hv = __floats2half2_rn(f0v, dv);   // lo=f0, hi=d
            __half2 hw = __floats2half2_rn(f0w, dw);
            uint2 cell;
            cell.x = *(unsigned int*)&hv;
            cell.y = *(unsigned int*)&hw;
            trow[cx] = cell;                           // full 8B, coalesced
        }
    }
}

// ---------------------------------------------------------------------------
// Kernel C (pair path): orbit backprojection, fp16 table, SH3=16 so EVERY
// output cache line is written by exactly one block, as full 64B lines:
//   P0/P2: row-coalesced dword stores (full rows of the quadrant).
//   P1/P3: LDS transpose (stride-20 pad) then aligned float4 full-line stores.
// XCD swizzle: block n -> xcd=n&7 owns slices [8*xcd, 8*xcd+8) so each XCD's
// table working set ~4.2MB fits its private L2.
// ---------------------------------------------------------------------------
__global__ __launch_bounds__(256, 4) void backproj_pairh_kernel(const uint2* __restrict__ tab,
                                                                const float2* __restrict__ trigp,
                                                                float* __restrict__ out) {
    __shared__ __align__(16) char smem[256 * TSTRIDE * 4];  // 20480 B: pbuf / transpose union
    __shared__ float2 trig_s[90];
    uint2* pbuf = (uint2*)smem;          // CHP*PW*8 = 11584 B during main loop
    float* ldsT = (float*)smem;          // 256*TSTRIDE dwords during epilogue

    int t = threadIdx.x;
    int n = blockIdx.x;                  // 0..1023
    int xcd = n & 7;
    int m = n >> 3;                      // 0..127
    int slice = (xcd << 3) | (m & 7);    // b*32 + r
    int strip = m >> 3;                  // 0..15
    int y0 = strip * SH3;                // rep-row offset in [0,256)
    const uint2* tslice = tab + (size_t)slice * (90 * PW);

    for (int i = t; i < 90; i += 256) trig_s[i] = trigp[i];

    float xc = (float)t + 0.5f;          // rep px = 256+t  ->  xc = px-255.5

    float acc0[SH3], acc1[SH3], acc2[SH3], acc3[SH3];
#pragma unroll
    for (int j = 0; j < SH3; ++j) { acc0[j] = 0.f; acc1[j] = 0.f; acc2[j] = 0.f; acc3[j] = 0.f; }

    for (int chunk = 0; chunk < NCHP; ++chunk) {
        __syncthreads();                 // previous chunk consumed (covers trig_s on chunk 0)
        const float4* src = (const float4*)(tslice + chunk * (CHP * PW));
        float4* dst = (float4*)pbuf;
        for (int i = t; i < (CHP * PW) / 2; i += 256) dst[i] = src[i];
        __syncthreads();
#pragma unroll
        for (int pa = 0; pa < CHP; ++pa) {
            float2 cs = trig_s[chunk * CHP + pa];
            const uint2* pb = pbuf + pa * PW + TCEN;
#pragma unroll
            for (int j = 0; j < SH3; ++j) {
                float ycj = (float)(y0 + j) + 0.5f;
                float ua = fmaf(xc, cs.x, fmaf(ycj, cs.y, -0.5f));   // x c + y s - .5
                float ub = fmaf(xc, cs.y, fmaf(-ycj, cs.x, -0.5f));  // x s - y c - .5
                float uma = -1.0f - ua;
                float umb = -1.0f - ub;

                float fa = floorf(ua);  int ma  = (int)fa;  float wa  = ua  - fa;
                float fm = floorf(uma); int mma = (int)fm;  float wma = uma - fm;
                float fb = floorf(ub);  int mb  = (int)fb;  float wb  = ub  - fb;
                float fn = floorf(umb); int mmb = (int)fn;  float wmb = umb - fn;

                uint2 qa  = pb[ma];
                uint2 qma = pb[mma];
                uint2 qb  = pb[mb];
                uint2 qmb = pb[mmb];
                __half2 qa0  = *(const __half2*)&qa.x,  qa1  = *(const __half2*)&qa.y;
                __half2 qma0 = *(const __half2*)&qma.x, qma1 = *(const __half2*)&qma.y;
                __half2 qb0  = *(const __half2*)&qb.x,  qb1  = *(const __half2*)&qb.y;
                __half2 qmb0 = *(const __half2*)&qmb.x, qmb1 = *(const __half2*)&qmb.y;

                acc0[j] = fmaf(wa,  __high2float(qa0),  acc0[j]) + __low2float(qa0);   // P0 @ v
                acc1[j] = fmaf(wa,  __high2float(qa1),  acc1[j]) + __low2float(qa1);   // P1 @ v+90
                acc2[j] = fmaf(wma, __high2float(qma0), acc2[j]) + __low2float(qma0);  // P2 @ v
                acc3[j] = fmaf(wma, __high2float(qma1), acc3[j]) + __low2float(qma1);  // P3 @ v+90
                acc1[j] = fmaf(wb,  __high2float(qb0),  acc1[j]) + __low2float(qb0);   // P1 @ v
                acc2[j] = fmaf(wb,  __high2float(qb1),  acc2[j]) + __low2float(qb1);   // P2 @ v+90
                acc3[j] = fmaf(wmb, __high2float(qmb0), acc3[j]) + __low2float(qmb0);  // P3 @ v
                acc0[j] = fmaf(wmb, __high2float(qmb1), acc0[j]) + __low2float(qmb1);  // P0 @ v+90
            }
        }
    }

    int px = 256 + t;
    size_t sbase = (size_t)slice * (512 * 512);

    // P0: rows 256+y0+j, cols 256..511 (lane-consecutive) - full-line dwords.
    // P2: rows 255-y0-j, cols 255-t (reverse-consecutive) - full-line dwords.
#pragma unroll
    for (int j = 0; j < SH3; ++j) {
        float v0 = acc0[j], v2 = acc2[j];
        out[sbase + (size_t)(256 + y0 + j) * 512 + px]       = v0 > 0.f ? v0 : 0.f;
        out[sbase + (size_t)(255 - y0 - j) * 512 + (255 - t)] = v2 > 0.f ? v2 : 0.f;
    }

    // P1: out rows 256+t, cols (240-y0)+i where value at i = acc1[15-i].
    __syncthreads();                     // main-loop pbuf reads done
#pragma unroll
    for (int j = 0; j < SH3; ++j) {
        float v1 = acc1[j];
        ldsT[t * TSTRIDE + (15 - j)] = v1 > 0.f ? v1 : 0.f;
    }
    __syncthreads();
    {
        int r = t >> 2, cg = (t & 3) * 4;
#pragma unroll
        for (int k = 0; k < 4; ++k) {
            int R = k * 64 + r;          // tile row = out row 256+R
            float4 vv = *(float4*)&ldsT[R * TSTRIDE + cg];
            *(float4*)(out + sbase + (size_t)(256 + R) * 512 + (240 - y0) + cg) = vv;
        }
    }

    // P3: out rows 255-t (store by out row), cols (256+y0)+j = acc3[j].
    __syncthreads();
#pragma unroll
    for (int j = 0; j < SH3; ++j) {
        float v3 = acc3[j];
        ldsT[(255 - t) * TSTRIDE + j] = v3 > 0.f ? v3 : 0.f;
    }
    __syncthreads();
    {
        int r = t >> 2, cg = (t & 3) * 4;
#pragma unroll
        for (int k = 0; k < 4; ++k) {
            int R = k * 64 + r;          // out row R
            float4 vv = *(float4*)&ldsT[R * TSTRIDE + cg];
            *(float4*)(out + sbase + (size_t)R * 512 + (256 + y0) + cg) = vv;
        }
    }
}

// ===========================================================================
// Fallback path (round-3 kernels) - used only if ws_size can't hold the table.
// ===========================================================================
__global__ __launch_bounds__(128) void conv_kernel(const float* __restrict__ sino,
                                                   const float* __restrict__ ws,
                                                   float* __restrict__ filt) {
    __shared__ float rows_s[16 * 512];
    __shared__ float h_s[1024];
    int t = threadIdx.x;
    int blk = blockIdx.x;
    int bv = blk >> 1;
    int half = blk & 1;
    int b = bv / 180;
    int v = bv - b * 180;

    const float4* src4 = (const float4*)(sino + (((size_t)bv * 32) + (size_t)half * 16) * 512);
    float4* rows4 = (float4*)rows_s;
    for (int i = t; i < 2048; i += 128) rows4[i] = src4[i];
    for (int i = t; i < 1024; i += 128) h_s[i] = ws[i];
    __syncthreads();

    int wave = t >> 6;
    int lane = t & 63;
    int row0 = wave * 8;

    float acc[8][8];
#pragma unroll
    for (int j = 0; j < 8; ++j)
#pragma unroll
        for (int i = 0; i < 8; ++i) acc[j][i] = 0.f;

    for (int k = 0; k < 512; k += 4) {
        float4 rv[8];
#pragma unroll
        for (int j = 0; j < 8; ++j)
            rv[j] = *(const float4*)&rows_s[(row0 + j) * 512 + k];
#pragma unroll
        for (int u = 0; u < 4; ++u) {
            float hv[8];
            int base = lane - (k + u) + 512;
#pragma unroll
            for (int i = 0; i < 8; ++i) hv[i] = h_s[base + 64 * i];
#pragma unroll
            for (int j = 0; j < 8; ++j) {
                float rj = (u == 0) ? rv[j].x : (u == 1) ? rv[j].y : (u == 2) ? rv[j].z : rv[j].w;
#pragma unroll
                for (int i = 0; i < 8; ++i) acc[j][i] = fmaf(rj, hv[i], acc[j][i]);
            }
        }
    }

#pragma unroll
    for (int j = 0; j < 8; ++j) {
        int r = half * 16 + row0 + j;
        float* dst = filt + (((size_t)b * 32 + r) * 180 + v) * 512;
#pragma unroll
        for (int i = 0; i < 8; ++i) dst[lane + 64 * i] = acc[j][i];
    }
}

__global__ __launch_bounds__(256) void backproj_kernel(const float* __restrict__ filt,
                                                       const float* __restrict__ trig,
                                                       float* __restrict__ out) {
    __shared__ float2 pbuf[CH2][PW];
    __shared__ float trig_s[360];
    int t = threadIdx.x;
    int slice = blockIdx.y;
    int strip = blockIdx.x;
    int y0 = strip * SH;
    int lane = t & 63;
    int wave = t >> 6;
    int x0 = wave * 128;
    const float* slice_p = filt + (size_t)slice * (180 * 512);

    for (int i = t; i < 360; i += 256) trig_s[i] = trig[i];

    float xc0 = (float)(x0 + lane) - 255.5f;
    float xc1 = xc0 + 64.0f;
    float yb0 = (float)y0 - 255.5f;

    float acc[2][SH];
#pragma unroll
    for (int g = 0; g < 2; ++g)
#pragma unroll
        for (int j = 0; j < SH; ++j) acc[g][j] = 0.f;

    for (int chunk = 0; chunk < NCHUNK2; ++chunk) {
        int v0 = chunk * CH2;
        __syncthreads();
#pragma unroll 1
        for (int a = 0; a < CH2; ++a) {
            const float* prow = slice_p + (v0 + a) * 512;
            for (int cx = t; cx < PW; cx += 256) {
                int s0 = cx - PADL;
                int i0 = min(max(s0, 0), 511);
                int i1 = min(max(s0 + 1, 0), 511);
                float f0 = prow[i0];
                float d = prow[i1] - f0;
                float m = (float)(cx - TCEN);
                pbuf[a][cx] = make_float2(fmaf(-m, d, f0), d);
            }
        }
        __syncthreads();
#pragma unroll 1
        for (int a = 0; a < CH2; ++a) {
            float cth = trig_s[v0 + a];
            float sth = trig_s[180 + v0 + a];
            float ybase = fmaf(yb0, sth, 255.5f + (float)PADL - (float)TCEN);
            float t0 = fmaf(xc0, cth, ybase);
            float t1 = fmaf(xc1, cth, ybase);
            const char* pb = (const char*)pbuf;
            int aoff = a * (PW * 8) + TCEN * 8;
#pragma unroll
            for (int j = 0; j < SH; ++j) {
                int m0 = (int)floorf(t0);
                float2 g0 = *(const float2*)(pb + (m0 * 8 + aoff));
                acc[0][j] = fmaf(t0, g0.y, acc[0][j]) + g0.x;
                t0 += sth;

                int m1 = (int)floorf(t1);
                float2 g1 = *(const float2*)(pb + (m1 * 8 + aoff));
                acc[1][j] = fmaf(t1, g1.y, acc[1][j]) + g1.x;
                t1 += sth;
            }
        }
    }

    size_t obase = ((size_t)slice * 512 + (size_t)y0) * 512;
#pragma unroll
    for (int j = 0; j < SH; ++j) {
        float v0o = acc[0][j];
        float v1o = acc[1][j];
        out[obase + (size_t)j * 512 + x0 + lane] = v0o > 0.f ? v0o : 0.f;
        out[obase + (size_t)j * 512 + x0 + 64 + lane] = v1o > 0.f ? v1o : 0.f;
    }
}

extern "C" void kernel_launch(void* const* d_in, const int* in_sizes, int n_in,
                              void* d_out, int out_size, void* d_ws, size_t ws_size,
                              hipStream_t stream) {
    const float* sino = (const float*)d_in[0];
    float* out = (float*)d_out;
    float* ws = (float*)d_ws;

    size_t tableBytes = (size_t)64 * 90 * PW * 8;              // uint2 cells
    size_t needed = TAB_OFF * sizeof(float) + tableBytes;      // ~33.4 MB

    precompute_kernel<<<2, 256, 0, stream>>>(ws);
    if (ws_size >= needed) {
        uint2* table = (uint2*)(ws + TAB_OFF);
        conv_pair_kernel<<<720, 128, 0, stream>>>(sino, ws, table);
        backproj_pairh_kernel<<<1024, 256, 0, stream>>>(table,
                                                        (const float2*)(ws + 1408), out);
    } else {
        float* filt = ws + FILT_OFF;
        conv_kernel<<<720, 128, 0, stream>>>(sino, ws, filt);
        backproj_kernel<<<dim3(32, 64), 256, 0, stream>>>(filt, ws + 1024, out);
    }
}